// Round 1
// baseline (135.888 us; speedup 1.0000x reference)
//
#include <hip/hip_runtime.h>
#include <hip/hip_bf16.h>
#include <math.h>

#define TOK 16384
#define HDIM 2048
#define NE 64
#define NB 4
#define SEQ 4096
#define KTOP 8

// ---------------------------------------------------------------------------
// K_A: gating GEMM. logits[t][e] = sum_h x[t][h] * w[e][h]
// Block: 256 threads, computes a 64-token x 64-expert tile over an H-slice.
// Grid: 256 token-blocks * nkh H-slices. Partial logits to ws (no atomics).
// LDS tiles stored transposed [k][t] / [k][e], stride 68 floats:
//   - rows 16B-aligned -> ds_read_b128 for the 4-wide fragments
//   - compute reads conflict-free (x: 4-addr broadcast, w: 64 consecutive floats)
//   - staging writes are 8-way conflicted (known cost, revisit later round)
// ---------------------------------------------------------------------------
__global__ __launch_bounds__(256) void gate_gemm(const float* __restrict__ x,
                                                 const float* __restrict__ w,
                                                 float* __restrict__ part,
                                                 int nkh) {
  const int bid = blockIdx.x;
  const int nblk_t = TOK / 64;            // 256
  const int kh = bid / nblk_t;
  const int tb = bid - kh * nblk_t;
  const int hspan = HDIM / nkh;
  const int h0 = kh * hspan;
  const int t0 = tb * 64;

  __shared__ float xs[64][68];            // [k][token]
  __shared__ float wsh[64][68];           // [k][expert]

  const int tid = threadIdx.x;
  const int tr = tid >> 4;                // token group 0..15
  const int tc = tid & 15;                // expert group 0..15

  float acc[4][4] = {};

  for (int kt = 0; kt < hspan; kt += 64) {
#pragma unroll
    for (int i = 0; i < 4; ++i) {
      int f4 = i * 256 + tid;             // 0..1023
      int row = f4 >> 4;                  // 0..63
      int c4 = (f4 & 15) << 2;            // 0,4,...,60
      float4 xv = *(const float4*)(x + (size_t)(t0 + row) * HDIM + h0 + kt + c4);
      xs[c4 + 0][row] = xv.x; xs[c4 + 1][row] = xv.y;
      xs[c4 + 2][row] = xv.z; xs[c4 + 3][row] = xv.w;
      float4 wv = *(const float4*)(w + (size_t)row * HDIM + h0 + kt + c4);
      wsh[c4 + 0][row] = wv.x; wsh[c4 + 1][row] = wv.y;
      wsh[c4 + 2][row] = wv.z; wsh[c4 + 3][row] = wv.w;
    }
    __syncthreads();
#pragma unroll
    for (int k = 0; k < 64; ++k) {
      float4 xa = *(const float4*)&xs[k][tr << 2];
      float4 wb = *(const float4*)&wsh[k][tc << 2];
      float xr[4] = {xa.x, xa.y, xa.z, xa.w};
      float wr[4] = {wb.x, wb.y, wb.z, wb.w};
#pragma unroll
      for (int i = 0; i < 4; ++i)
#pragma unroll
        for (int j = 0; j < 4; ++j)
          acc[i][j] = fmaf(xr[i], wr[j], acc[i][j]);
    }
    __syncthreads();
  }

#pragma unroll
  for (int i = 0; i < 4; ++i) {
    float4 v = make_float4(acc[i][0], acc[i][1], acc[i][2], acc[i][3]);
    *(float4*)(part + (size_t)kh * TOK * NE +
               (size_t)(t0 + (tr << 2) + i) * NE + (tc << 2)) = v;
  }
}

// ---------------------------------------------------------------------------
// K_C: softmax + top-8 + stats. One wave (64 threads) per 64 tokens.
// Scores staged transposed [e][t] stride 65 -> conflict-free loads & scans.
// ---------------------------------------------------------------------------
__global__ __launch_bounds__(64) void gate_topk(const float* __restrict__ part,
                                                int nkh,
                                                float* __restrict__ out,
                                                float* __restrict__ ce,
                                                float* __restrict__ ssum) {
  const int bid = blockIdx.x;
  const int tid = threadIdx.x;
  const int t0 = bid * 64;
  const int b = t0 >> 12;                 // t0 / 4096

  __shared__ float sc[64][65];            // [expert][token]
  __shared__ float hist[64];
  hist[tid] = 0.f;

  for (int i = 0; i < 64; ++i) {
    size_t idx = (size_t)(t0 + i) * NE + tid;
    float v = part[idx];
    if (nkh == 2) v += part[(size_t)TOK * NE + idx];
    sc[tid][i] = v;                       // expert=tid, token=i
  }
  __syncthreads();

  // softmax over experts for token `tid`
  float m = -3.4e38f;
#pragma unroll
  for (int e = 0; e < 64; ++e) m = fmaxf(m, sc[e][tid]);
  float sum = 0.f;
#pragma unroll
  for (int e = 0; e < 64; ++e) {
    float p = expf(sc[e][tid] - m);
    sum += p;
    sc[e][tid] = p;
  }
  float inv_sum = 1.f / sum;
#pragma unroll
  for (int e = 0; e < 64; ++e) sc[e][tid] *= inv_sum;

  // top-8, strict > scan => ties resolve to lowest index (lax.top_k order)
  unsigned long long used = 0ull;
  float wsel[KTOP];
  int isel[KTOP];
  float wsum = 0.f;
#pragma unroll
  for (int j = 0; j < KTOP; ++j) {
    float best = -1.f;
    int bi = 0;
    for (int e = 0; e < 64; ++e) {
      if (!((used >> e) & 1ull)) {
        float v = sc[e][tid];
        if (v > best) { best = v; bi = e; }
      }
    }
    used |= 1ull << bi;
    wsel[j] = best;
    isel[j] = bi;
    wsum += best;
  }
  float winv = 1.f / (wsum + 1e-20f);

#pragma unroll
  for (int j = 0; j < KTOP; ++j) {
    out[(size_t)(t0 + tid) * KTOP + j] = (float)isel[j];
    out[(size_t)TOK * KTOP + (size_t)(t0 + tid) * KTOP + j] = wsel[j] * winv;
    atomicAdd(&hist[isel[j]], 1.f);
  }
  __syncthreads();

  // per-(batch, expert) score sum: thread = expert, sum its 64 tokens
  float s = 0.f;
  for (int t = 0; t < 64; ++t) s += sc[tid][t];
  atomicAdd(&ssum[b * 64 + tid], s);
  atomicAdd(&ce[b * 64 + tid], hist[tid]);
}

// ---------------------------------------------------------------------------
// K_D: finalize expert_loads + aux_loss
// ---------------------------------------------------------------------------
__global__ __launch_bounds__(64) void gate_final(const float* __restrict__ ce,
                                                 const float* __restrict__ ssum,
                                                 float* __restrict__ out) {
  const int e = threadIdx.x;              // 64 threads
  float loads = 0.f, aux = 0.f;
#pragma unroll
  for (int b = 0; b < NB; ++b) {
    float c = ce[b * 64 + e];
    loads += c;
    aux += (c / 512.0f) * (ssum[b * 64 + e] / 4096.0f);  // (S*K/E)=512, S=4096
  }
  out[(size_t)2 * TOK * KTOP + 1 + e] = loads;
#pragma unroll
  for (int off = 32; off > 0; off >>= 1) aux += __shfl_down(aux, off);
  if (e == 0) out[(size_t)2 * TOK * KTOP] = aux * (0.1f / 4.0f);  // ALPHA / B
}

extern "C" void kernel_launch(void* const* d_in, const int* in_sizes, int n_in,
                              void* d_out, int out_size, void* d_ws, size_t ws_size,
                              hipStream_t stream) {
  const float* x = (const float*)d_in[0];
  const float* w = (const float*)d_in[1];
  float* out = (float*)d_out;

  float* part = (float*)d_ws;
  const size_t part_elems = (size_t)TOK * NE;     // 1 Mi floats = 4 MB
  int nkh = 2;
  if (ws_size < (2 * part_elems + 512) * sizeof(float)) nkh = 1;
  float* ce = part + (size_t)nkh * part_elems;    // [NB][NE]
  float* ssum = ce + NB * NE;                     // [NB][NE]

  hipMemsetAsync(ce, 0, 2 * NB * NE * sizeof(float), stream);
  gate_gemm<<<dim3(256 * nkh), dim3(256), 0, stream>>>(x, w, part, nkh);
  gate_topk<<<dim3(256), dim3(64), 0, stream>>>(part, nkh, out, ce, ssum);
  gate_final<<<dim3(1), dim3(64), 0, stream>>>(ce, ssum, out);
}

// Round 3
// 90.820 us; speedup vs baseline: 1.4962x; 1.4962x over previous
//
#include <hip/hip_runtime.h>
#include <hip/hip_bf16.h>
#include <math.h>

#define TOK 16384
#define HDIM 2048
#define NE 64
#define NB 4
#define KTOP 8
#define KC 64
#define NC (HDIM / KC)   // 32 chunks

typedef __attribute__((ext_vector_type(8))) __bf16 bf16x8;
typedef __attribute__((ext_vector_type(4))) float f32x4;
typedef unsigned int uint;

__device__ __forceinline__ uint asu(float f) { union { float f; uint u; } c; c.f = f; return c.u; }
__device__ __forceinline__ float asf(uint u) { union { uint u; float f; } c; c.u = u; return c.f; }

// Exact 3-way bf16 split: h = bits 1-8 of mantissa, m = 9-16, l = 17-24.
// Both residual subtractions are exact in f32, so h+m+l == x bitwise.
__device__ __forceinline__ void split3(float v, uint& h, uint& m, uint& l) {
  uint u = asu(v);
  h = u & 0xffff0000u;
  float d = v - asf(h);
  m = asu(d) & 0xffff0000u;
  float d2 = d - asf(m);
  l = asu(d2);
}

// ---------------------------------------------------------------------------
// Pre-split W (64 x 2048 f32) into 3 bf16 planes in ws. Run once per launch.
// ---------------------------------------------------------------------------
__global__ __launch_bounds__(256) void wsplit(const float* __restrict__ w,
                                              ushort* __restrict__ wh,
                                              ushort* __restrict__ wm,
                                              ushort* __restrict__ wl) {
  int g = blockIdx.x * 256 + threadIdx.x;          // 0..32767, 4 floats each
  float4 v = *(const float4*)(w + (size_t)g * 4);
  uint h0, m0, l0, h1, m1, l1, h2, m2, l2, h3, m3, l3;
  split3(v.x, h0, m0, l0); split3(v.y, h1, m1, l1);
  split3(v.z, h2, m2, l2); split3(v.w, h3, m3, l3);
  *(ushort4*)(wh + (size_t)g * 4) =
      make_ushort4((ushort)(h0 >> 16), (ushort)(h1 >> 16), (ushort)(h2 >> 16), (ushort)(h3 >> 16));
  *(ushort4*)(wm + (size_t)g * 4) =
      make_ushort4((ushort)(m0 >> 16), (ushort)(m1 >> 16), (ushort)(m2 >> 16), (ushort)(m3 >> 16));
  *(ushort4*)(wl + (size_t)g * 4) =
      make_ushort4((ushort)(l0 >> 16), (ushort)(l1 >> 16), (ushort)(l2 >> 16), (ushort)(l3 >> 16));
}

// ---------------------------------------------------------------------------
// Fused MoE gate. Block = 512 threads (8 waves) = 64 tokens x 64 experts,
// full K=2048. Exact 3-way bf16 split, 6 MFMA products (err < f32 accum).
// LDS planes XOR-swizzled (byte ^= (row&7)<<4) on write and read.
// Each wave owns a 16-token x 32-expert quadrant (2 C-fragments).
// ---------------------------------------------------------------------------
__global__ __launch_bounds__(512) void gate_fused(const float* __restrict__ x,
                                                  const ushort* __restrict__ wh,
                                                  const ushort* __restrict__ wm,
                                                  const ushort* __restrict__ wl,
                                                  float* __restrict__ out,
                                                  float* __restrict__ ce,
                                                  float* __restrict__ ssum) {
  __shared__ char lds[49152];                       // 6 planes x 8 KB
  __shared__ float hist[NE];

  const int tid = threadIdx.x;
  const int bid = blockIdx.x;
  const int t0 = bid * 64;
  const int b = bid >> 6;
  const int lane = tid & 63;
  const int wid = tid >> 6;

  if (tid < NE) hist[tid] = 0.f;

  char* XH = lds;          char* XM = lds + 8192;  char* XL = lds + 16384;
  char* WHs = lds + 24576; char* WMs = lds + 32768; char* WLs = lds + 40960;

  // X staging coords: 2 iters, f4 = i*512+tid; row = f4>>4; col4 = (f4&15)*4
  int xrow[2], xad[2], xcol[2];
#pragma unroll
  for (int i = 0; i < 2; ++i) {
    int f4 = i * 512 + tid;
    xrow[i] = f4 >> 4;
    xcol[i] = (f4 & 15) << 2;
    int cb = (f4 & 15) << 3;
    xad[i] = xrow[i] * 128 + (cb ^ ((xrow[i] & 7) << 4));
  }
  // W staging coords: row = tid>>3 (0..63), 16B slot = tid&7
  const int wrow = tid >> 3;
  const int wad = wrow * 128 + (((tid & 7) << 4) ^ ((wrow & 7) << 4));
  const size_t wsrc = (size_t)wrow * HDIM + ((tid & 7) << 3);  // ushort elems

  // MFMA fragment coords
  const int arow = ((wid >> 1) << 4) + (lane & 15);
  const int abase = arow * 128, axor = (arow & 7) << 4;
  const int erow0 = ((wid & 1) << 5) + (lane & 15);
  int bbase[2], bxor[2];
#pragma unroll
  for (int f = 0; f < 2; ++f) {
    int br = erow0 + f * 16;
    bbase[f] = br * 128; bxor[f] = (br & 7) << 4;
  }
  const int kq = (lane >> 4) << 4;

  const float* xb = x + (size_t)t0 * HDIM;
  float4 xr[2];
  uint4 wr[3];

#define LOADC(c)                                                              \
  {                                                                           \
    _Pragma("unroll")                                                         \
    for (int i = 0; i < 2; ++i)                                               \
      xr[i] = *(const float4*)(xb + (size_t)xrow[i] * HDIM + (c) * KC + xcol[i]); \
    wr[0] = *(const uint4*)(wh + wsrc + (c) * KC);                            \
    wr[1] = *(const uint4*)(wm + wsrc + (c) * KC);                            \
    wr[2] = *(const uint4*)(wl + wsrc + (c) * KC);                            \
  }

  f32x4 acc[2] = {{0.f, 0.f, 0.f, 0.f}, {0.f, 0.f, 0.f, 0.f}};

  LOADC(0);
  for (int c = 0; c < NC; ++c) {
    // stage X (convert to 3 exact bf16 planes) + W (pre-split)
#pragma unroll
    for (int i = 0; i < 2; ++i) {
      uint h0, m0, l0, h1, m1, l1, h2, m2, l2, h3, m3, l3;
      split3(xr[i].x, h0, m0, l0); split3(xr[i].y, h1, m1, l1);
      split3(xr[i].z, h2, m2, l2); split3(xr[i].w, h3, m3, l3);
      *(uint2*)(XH + xad[i]) = make_uint2((h0 >> 16) | h1, (h2 >> 16) | h3);
      *(uint2*)(XM + xad[i]) = make_uint2((m0 >> 16) | m1, (m2 >> 16) | m3);
      *(uint2*)(XL + xad[i]) = make_uint2((l0 >> 16) | l1, (l2 >> 16) | l3);
    }
    *(uint4*)(WHs + wad) = wr[0];
    *(uint4*)(WMs + wad) = wr[1];
    *(uint4*)(WLs + wad) = wr[2];
    __syncthreads();
    if (c + 1 < NC) LOADC(c + 1);       // overlap next-chunk loads with MFMA
#pragma unroll
    for (int ks = 0; ks < 2; ++ks) {
      int kb = ks * 64 + kq;
      bf16x8 ah = *(const bf16x8*)(XH + abase + (kb ^ axor));
      bf16x8 am = *(const bf16x8*)(XM + abase + (kb ^ axor));
      bf16x8 al = *(const bf16x8*)(XL + abase + (kb ^ axor));
#pragma unroll
      for (int f = 0; f < 2; ++f) {
        bf16x8 bh = *(const bf16x8*)(WHs + bbase[f] + (kb ^ bxor[f]));
        bf16x8 bm = *(const bf16x8*)(WMs + bbase[f] + (kb ^ bxor[f]));
        bf16x8 bl = *(const bf16x8*)(WLs + bbase[f] + (kb ^ bxor[f]));
        acc[f] = __builtin_amdgcn_mfma_f32_16x16x32_bf16(ah, bh, acc[f], 0, 0, 0);
        acc[f] = __builtin_amdgcn_mfma_f32_16x16x32_bf16(ah, bm, acc[f], 0, 0, 0);
        acc[f] = __builtin_amdgcn_mfma_f32_16x16x32_bf16(am, bh, acc[f], 0, 0, 0);
        acc[f] = __builtin_amdgcn_mfma_f32_16x16x32_bf16(ah, bl, acc[f], 0, 0, 0);
        acc[f] = __builtin_amdgcn_mfma_f32_16x16x32_bf16(al, bh, acc[f], 0, 0, 0);
        acc[f] = __builtin_amdgcn_mfma_f32_16x16x32_bf16(am, bm, acc[f], 0, 0, 0);
      }
    }
    __syncthreads();
  }
#undef LOADC

  // scores overlay the GEMM LDS. C layout: col(=expert)=lane&15,
  // row(=token)=(lane>>4)*4+reg  [m89-verified]
  float (*sc)[65] = (float(*)[65])lds;
#pragma unroll
  for (int f = 0; f < 2; ++f) {
    int e = erow0 + f * 16;
    int tk = ((wid >> 1) << 4) + ((lane >> 4) << 2);
#pragma unroll
    for (int r = 0; r < 4; ++r) sc[e][tk + r] = acc[f][r];
  }
  __syncthreads();

  // softmax + top-8: 8 lanes per token, 8 experts per lane
  const int t = tid >> 3;
  const int j = tid & 7;
  float p[8];
#pragma unroll
  for (int i = 0; i < 8; ++i) p[i] = sc[j * 8 + i][t];

  float m = p[0];
#pragma unroll
  for (int i = 1; i < 8; ++i) m = fmaxf(m, p[i]);
  m = fmaxf(m, __shfl_xor(m, 1, 8));
  m = fmaxf(m, __shfl_xor(m, 2, 8));
  m = fmaxf(m, __shfl_xor(m, 4, 8));
  float s = 0.f;
#pragma unroll
  for (int i = 0; i < 8; ++i) { p[i] = __expf(p[i] - m); s += p[i]; }
  s += __shfl_xor(s, 1, 8);
  s += __shfl_xor(s, 2, 8);
  s += __shfl_xor(s, 4, 8);
  float inv = 1.f / s;
#pragma unroll
  for (int i = 0; i < 8; ++i) { p[i] *= inv; sc[j * 8 + i][t] = p[i]; }

  // top-8: per-lane strict-> scan (lowest idx on tie), 8-lane (val,idx) reduce
  unsigned used = 0;
  float wsum = 0.f;
  float wv[KTOP];
  int wi_[KTOP];
#pragma unroll
  for (int sel = 0; sel < KTOP; ++sel) {
    float bv = -1.f;
    int bi = 0;
#pragma unroll
    for (int i = 0; i < 8; ++i) {
      bool ok = !((used >> i) & 1u);
      if (ok && p[i] > bv) { bv = p[i]; bi = i; }
    }
    int ge = j * 8 + bi;
#pragma unroll
    for (int mk = 1; mk < 8; mk <<= 1) {
      float ov = __shfl_xor(bv, mk, 8);
      int og = __shfl_xor(ge, mk, 8);
      if (ov > bv || (ov == bv && og < ge)) { bv = ov; ge = og; }
    }
    if ((ge >> 3) == j) used |= 1u << (ge & 7);
    wv[sel] = bv;
    wi_[sel] = ge;
    wsum += bv;
  }
  if (j == 0) {
    float winv = 1.f / (wsum + 1e-20f);
#pragma unroll
    for (int sel = 0; sel < KTOP; ++sel) {
      out[(size_t)(t0 + t) * KTOP + sel] = (float)wi_[sel];
      out[(size_t)TOK * KTOP + (size_t)(t0 + t) * KTOP + sel] = wv[sel] * winv;
      atomicAdd(&hist[wi_[sel]], 1.f);
    }
  }
  __syncthreads();

  if (tid < NE) {
    float ssl = 0.f;
#pragma unroll
    for (int tt = 0; tt < 64; ++tt) ssl += sc[tid][tt];
    atomicAdd(&ssum[b * NE + tid], ssl);
    atomicAdd(&ce[b * NE + tid], hist[tid]);
  }
}

// ---------------------------------------------------------------------------
// Finalize expert_loads + aux_loss
// ---------------------------------------------------------------------------
__global__ __launch_bounds__(64) void gate_final(const float* __restrict__ ce,
                                                 const float* __restrict__ ssum,
                                                 float* __restrict__ out) {
  const int e = threadIdx.x;
  float loads = 0.f, aux = 0.f;
#pragma unroll
  for (int b = 0; b < NB; ++b) {
    float c = ce[b * 64 + e];
    loads += c;
    aux += (c / 512.0f) * (ssum[b * 64 + e] / 4096.0f);  // (S*K/E)=512, S=4096
  }
  out[(size_t)2 * TOK * KTOP + 1 + e] = loads;
#pragma unroll
  for (int off = 32; off > 0; off >>= 1) aux += __shfl_down(aux, off);
  if (e == 0) out[(size_t)2 * TOK * KTOP] = aux * (0.1f / 4.0f);  // ALPHA/B
}

extern "C" void kernel_launch(void* const* d_in, const int* in_sizes, int n_in,
                              void* d_out, int out_size, void* d_ws, size_t ws_size,
                              hipStream_t stream) {
  const float* x = (const float*)d_in[0];
  const float* w = (const float*)d_in[1];
  float* out = (float*)d_out;

  ushort* wh = (ushort*)d_ws;                      // 3 planes x 256 KB
  ushort* wm = wh + (size_t)NE * HDIM;
  ushort* wl = wm + (size_t)NE * HDIM;
  float* ce = (float*)(wl + (size_t)NE * HDIM);    // [NB][NE]
  float* ssum = ce + NB * NE;                      // [NB][NE]

  hipMemsetAsync(ce, 0, 2 * NB * NE * sizeof(float), stream);
  wsplit<<<dim3(128), dim3(256), 0, stream>>>(w, wh, wm, wl);
  gate_fused<<<dim3(TOK / 64), dim3(512), 0, stream>>>(x, wh, wm, wl, out, ce, ssum);
  gate_final<<<dim3(1), dim3(64), 0, stream>>>(ce, ssum, out);
}

// Round 4
// 60.716 us; speedup vs baseline: 2.2381x; 1.4958x over previous
//
#include <hip/hip_runtime.h>
#include <hip/hip_bf16.h>
#include <math.h>

#define TOK 16384
#define HDIM 2048
#define NE 64
#define NB 4
#define KTOP 8
#define KC 64
#define NC (HDIM / KC)   // 32 chunks

typedef __attribute__((ext_vector_type(8))) __bf16 bf16x8;
typedef __attribute__((ext_vector_type(4))) float f32x4;
typedef unsigned int uint;

__device__ __forceinline__ uint asu(float f) { union { float f; uint u; } c; c.f = f; return c.u; }
__device__ __forceinline__ float asf(uint u) { union { uint u; float f; } c; c.u = u; return c.f; }

// Exact 3-way bf16 split: h+m+l == x bitwise (8 mantissa bits per plane).
__device__ __forceinline__ void split3(float v, uint& h, uint& m, uint& l) {
  uint u = asu(v);
  h = u & 0xffff0000u;
  float d = v - asf(h);
  m = asu(d) & 0xffff0000u;
  float d2 = d - asf(m);
  l = asu(d2);
}

// 8 floats (one A-fragment k-slot) -> 3 bf16x8 planes, in-register.
__device__ __forceinline__ void split8(float4 a, float4 b,
                                       bf16x8& h8, bf16x8& m8, bf16x8& l8) {
  union { uint4 u; bf16x8 v; } H, M, L;
  uint h0, m0, l0, h1, m1, l1;
  split3(a.x, h0, m0, l0); split3(a.y, h1, m1, l1);
  H.u.x = (h0 >> 16) | (h1 & 0xffff0000u);
  M.u.x = (m0 >> 16) | (m1 & 0xffff0000u);
  L.u.x = (l0 >> 16) | (l1 & 0xffff0000u);
  split3(a.z, h0, m0, l0); split3(a.w, h1, m1, l1);
  H.u.y = (h0 >> 16) | (h1 & 0xffff0000u);
  M.u.y = (m0 >> 16) | (m1 & 0xffff0000u);
  L.u.y = (l0 >> 16) | (l1 & 0xffff0000u);
  split3(b.x, h0, m0, l0); split3(b.y, h1, m1, l1);
  H.u.z = (h0 >> 16) | (h1 & 0xffff0000u);
  M.u.z = (m0 >> 16) | (m1 & 0xffff0000u);
  L.u.z = (l0 >> 16) | (l1 & 0xffff0000u);
  split3(b.z, h0, m0, l0); split3(b.w, h1, m1, l1);
  H.u.w = (h0 >> 16) | (h1 & 0xffff0000u);
  M.u.w = (m0 >> 16) | (m1 & 0xffff0000u);
  L.u.w = (l0 >> 16) | (l1 & 0xffff0000u);
  h8 = H.v; m8 = M.v; l8 = L.v;
}

__device__ __forceinline__ void gl_lds16(const void* g, void* l) {
  __builtin_amdgcn_global_load_lds(
      (const __attribute__((address_space(1))) void*)g,
      (__attribute__((address_space(3))) void*)l, 16, 0, 0);
}

// ---------------------------------------------------------------------------
// wsplit: pack W into B-fragment order, 3 exact bf16 planes.
// wpk[c][idx][lane]*16B, idx = ((ks*2+half)*2+f2)*3 + plane  (24 KB / chunk)
// Fragment (c,ks,half,f2,plane,lane): e = half*32+f2*16+(lane&15),
//                                     k = c*64+ks*32+(lane>>4)*8
// ---------------------------------------------------------------------------
__global__ __launch_bounds__(256) void wsplit(const float* __restrict__ w,
                                              char* __restrict__ wpk) {
  int t = blockIdx.x * 256 + threadIdx.x;    // 16384 threads
  int lane = t & 63;
  int f2 = (t >> 6) & 1, half = (t >> 7) & 1, ks = (t >> 8) & 1, c = t >> 9;
  int e = half * 32 + f2 * 16 + (lane & 15);
  int k = c * 64 + ks * 32 + ((lane >> 4) << 3);
  const float* p = w + (size_t)e * HDIM + k;
  bf16x8 h8, m8, l8;
  split8(*(const float4*)p, *(const float4*)(p + 4), h8, m8, l8);
  union { bf16x8 v; uint4 u; } H, M, L;
  H.v = h8; M.v = m8; L.v = l8;
  size_t base = ((size_t)c * 24 + (size_t)(((ks * 2 + half) * 2 + f2) * 3)) * 1024
                + (size_t)lane * 16;
  *(uint4*)(wpk + base) = H.u;
  *(uint4*)(wpk + base + 1024) = M.u;
  *(uint4*)(wpk + base + 2048) = L.u;
}

// ---------------------------------------------------------------------------
// Fused gate. 256 blocks x 512 thr (8 waves). Wave = 16 tokens x 32 experts.
// X: global->reg (A-fragment native layout), depth-2 prefetch, split3 in-reg.
// W: global_load_lds (16B) into 2x24KB LDS dbuf, fragment-linear layout.
// One raw s_barrier per chunk; counted vmcnt(4) keeps X in flight across it.
// ---------------------------------------------------------------------------
__global__ __launch_bounds__(512) void gate_fused(const float* __restrict__ x,
                                                  const char* __restrict__ wpk,
                                                  float* __restrict__ out,
                                                  float* __restrict__ ce,
                                                  float* __restrict__ ssum) {
  __shared__ __align__(16) char lds[49152];   // W dbuf: 2 x 24 KB
  __shared__ float hist[NE];

  const int tid = threadIdx.x;
  const int bid = blockIdx.x;
  const int t0 = bid * 64;
  const int b = bid >> 6;
  const int lane = tid & 63;
  const int wid = tid >> 6;
  const int half = wid & 1;                   // expert half
  const int tg = (wid >> 1) << 4;             // token group base

  if (tid < NE) hist[tid] = 0.f;

  char* buf0 = lds;
  char* buf1 = lds + 24576;

  // per-lane X base: row = t0+tg+(lane&15), k-slot offset (lane>>4)*8
  const float* xrow = x + (size_t)(t0 + tg + (lane & 15)) * HDIM + ((lane >> 4) << 3);

  f32x4 acc[2] = {{0.f, 0.f, 0.f, 0.f}, {0.f, 0.f, 0.f, 0.f}};

  // ---- prologue: W(0) -> buf0; X(0) -> xa; X(1) -> xb
  {
    const char* wsp0 = wpk + (size_t)lane * 16;
    gl_lds16(wsp0 + (0 * 8 + wid) * 1024, buf0 + (0 * 8 + wid) * 1024);
    gl_lds16(wsp0 + (1 * 8 + wid) * 1024, buf0 + (1 * 8 + wid) * 1024);
    gl_lds16(wsp0 + (2 * 8 + wid) * 1024, buf0 + (2 * 8 + wid) * 1024);
  }
  float4 xa0 = *(const float4*)(xrow);
  float4 xa1 = *(const float4*)(xrow + 4);
  float4 xa2 = *(const float4*)(xrow + 32);
  float4 xa3 = *(const float4*)(xrow + 36);
  float4 xb0 = *(const float4*)(xrow + 64);
  float4 xb1 = *(const float4*)(xrow + 68);
  float4 xb2 = *(const float4*)(xrow + 96);
  float4 xb3 = *(const float4*)(xrow + 100);
  asm volatile("s_waitcnt vmcnt(4)" ::: "memory");  // W(0)+X(0) done; X(1) in flight
  __builtin_amdgcn_s_barrier();
  asm volatile("" ::: "memory");

#define CHUNK(c, X0, X1, X2, X3, BR, BW)                                        \
  {                                                                             \
    if ((c) + 1 < NC) {   /* 1: stage W(c+1) -> BW */                           \
      const char* wsp = wpk + (size_t)((c) + 1) * 24576 + (size_t)lane * 16;    \
      gl_lds16(wsp + (0 * 8 + wid) * 1024, BW + (0 * 8 + wid) * 1024);          \
      gl_lds16(wsp + (1 * 8 + wid) * 1024, BW + (1 * 8 + wid) * 1024);          \
      gl_lds16(wsp + (2 * 8 + wid) * 1024, BW + (2 * 8 + wid) * 1024);          \
    }                                                                           \
    bf16x8 ah0, am0, al0, ah1, am1, al1;     /* 2: split X(c) */                \
    split8(X0, X1, ah0, am0, al0);                                              \
    split8(X2, X3, ah1, am1, al1);                                              \
    if ((c) + 2 < NC) {   /* 3: issue X(c+2) */                                 \
      const float* xp = xrow + ((c) + 2) * 64;                                  \
      X0 = *(const float4*)(xp);                                                \
      X1 = *(const float4*)(xp + 4);                                            \
      X2 = *(const float4*)(xp + 32);                                           \
      X3 = *(const float4*)(xp + 36);                                           \
    }                                                                           \
    _Pragma("unroll")     /* 4: MFMA on BR = W(c) */                            \
    for (int f2 = 0; f2 < 2; ++f2) {                                            \
      const char* bb0 = BR + (size_t)(((0 * 2 + half) * 2 + f2) * 3) * 1024 + lane * 16; \
      bf16x8 bh = *(const bf16x8*)(bb0);                                        \
      bf16x8 bm = *(const bf16x8*)(bb0 + 1024);                                 \
      bf16x8 bl = *(const bf16x8*)(bb0 + 2048);                                 \
      acc[f2] = __builtin_amdgcn_mfma_f32_16x16x32_bf16(ah0, bh, acc[f2], 0, 0, 0); \
      acc[f2] = __builtin_amdgcn_mfma_f32_16x16x32_bf16(ah0, bm, acc[f2], 0, 0, 0); \
      acc[f2] = __builtin_amdgcn_mfma_f32_16x16x32_bf16(am0, bh, acc[f2], 0, 0, 0); \
      acc[f2] = __builtin_amdgcn_mfma_f32_16x16x32_bf16(ah0, bl, acc[f2], 0, 0, 0); \
      acc[f2] = __builtin_amdgcn_mfma_f32_16x16x32_bf16(al0, bh, acc[f2], 0, 0, 0); \
      acc[f2] = __builtin_amdgcn_mfma_f32_16x16x32_bf16(am0, bm, acc[f2], 0, 0, 0); \
      const char* bb1 = BR + (size_t)(((1 * 2 + half) * 2 + f2) * 3) * 1024 + lane * 16; \
      bf16x8 kh = *(const bf16x8*)(bb1);                                        \
      bf16x8 km = *(const bf16x8*)(bb1 + 1024);                                 \
      bf16x8 kl = *(const bf16x8*)(bb1 + 2048);                                 \
      acc[f2] = __builtin_amdgcn_mfma_f32_16x16x32_bf16(ah1, kh, acc[f2], 0, 0, 0); \
      acc[f2] = __builtin_amdgcn_mfma_f32_16x16x32_bf16(ah1, km, acc[f2], 0, 0, 0); \
      acc[f2] = __builtin_amdgcn_mfma_f32_16x16x32_bf16(am1, kh, acc[f2], 0, 0, 0); \
      acc[f2] = __builtin_amdgcn_mfma_f32_16x16x32_bf16(ah1, kl, acc[f2], 0, 0, 0); \
      acc[f2] = __builtin_amdgcn_mfma_f32_16x16x32_bf16(al1, kh, acc[f2], 0, 0, 0); \
      acc[f2] = __builtin_amdgcn_mfma_f32_16x16x32_bf16(am1, km, acc[f2], 0, 0, 0); \
    }                                                                           \
    /* 5/6: W(c+1) landed for THIS wave, then barrier -> visible to all */      \
    if ((c) < NC - 2) { asm volatile("s_waitcnt vmcnt(4)" ::: "memory"); }      \
    else              { asm volatile("s_waitcnt vmcnt(0)" ::: "memory"); }      \
    __builtin_amdgcn_s_barrier();                                               \
    asm volatile("" ::: "memory");                                              \
  }

#pragma unroll 1
  for (int cc = 0; cc < NC; cc += 2) {
    CHUNK(cc,     xa0, xa1, xa2, xa3, buf0, buf1);
    CHUNK(cc + 1, xb0, xb1, xb2, xb3, buf1, buf0);
  }
#undef CHUNK

  // scores -> LDS overlay (buf0 region; last chunk read buf1, disjoint).
  // C layout: col(=expert)=lane&15, row(=token)=(lane>>4)*4+reg  [m89]
  float (*sc)[65] = (float(*)[65])lds;
#pragma unroll
  for (int f2 = 0; f2 < 2; ++f2) {
    int e = half * 32 + f2 * 16 + (lane & 15);
    int tk = tg + ((lane >> 4) << 2);
    sc[e][tk + 0] = acc[f2][0];
    sc[e][tk + 1] = acc[f2][1];
    sc[e][tk + 2] = acc[f2][2];
    sc[e][tk + 3] = acc[f2][3];
  }
  __syncthreads();

  // softmax + top-8: 8 lanes per token, 8 experts per lane
  const int t = tid >> 3;
  const int j = tid & 7;
  float p[8];
#pragma unroll
  for (int i = 0; i < 8; ++i) p[i] = sc[j * 8 + i][t];

  float m = p[0];
#pragma unroll
  for (int i = 1; i < 8; ++i) m = fmaxf(m, p[i]);
  m = fmaxf(m, __shfl_xor(m, 1, 8));
  m = fmaxf(m, __shfl_xor(m, 2, 8));
  m = fmaxf(m, __shfl_xor(m, 4, 8));
  float s = 0.f;
#pragma unroll
  for (int i = 0; i < 8; ++i) { p[i] = __expf(p[i] - m); s += p[i]; }
  s += __shfl_xor(s, 1, 8);
  s += __shfl_xor(s, 2, 8);
  s += __shfl_xor(s, 4, 8);
  float inv = 1.f / s;
#pragma unroll
  for (int i = 0; i < 8; ++i) { p[i] *= inv; sc[j * 8 + i][t] = p[i]; }

  // top-8: strict-> scan (lowest idx on tie), 8-lane (val,idx) reduce
  unsigned used = 0;
  float wsum = 0.f;
  float wv[KTOP];
  int wi_[KTOP];
#pragma unroll
  for (int sel = 0; sel < KTOP; ++sel) {
    float bv = -1.f;
    int bi = 0;
#pragma unroll
    for (int i = 0; i < 8; ++i) {
      bool ok = !((used >> i) & 1u);
      if (ok && p[i] > bv) { bv = p[i]; bi = i; }
    }
    int ge = j * 8 + bi;
#pragma unroll
    for (int mk = 1; mk < 8; mk <<= 1) {
      float ov = __shfl_xor(bv, mk, 8);
      int og = __shfl_xor(ge, mk, 8);
      if (ov > bv || (ov == bv && og < ge)) { bv = ov; ge = og; }
    }
    if ((ge >> 3) == j) used |= 1u << (ge & 7);
    wv[sel] = bv;
    wi_[sel] = ge;
    wsum += bv;
  }
  if (j == 0) {
    float winv = 1.f / (wsum + 1e-20f);
#pragma unroll
    for (int sel = 0; sel < KTOP; ++sel) {
      out[(size_t)(t0 + t) * KTOP + sel] = (float)wi_[sel];
      out[(size_t)TOK * KTOP + (size_t)(t0 + t) * KTOP + sel] = wv[sel] * winv;
      atomicAdd(&hist[wi_[sel]], 1.f);
    }
  }
  __syncthreads();

  if (tid < NE) {
    float ssl = 0.f;
#pragma unroll
    for (int tt = 0; tt < 64; ++tt) ssl += sc[tid][tt];
    atomicAdd(&ssum[b * NE + tid], ssl);
    atomicAdd(&ce[b * NE + tid], hist[tid]);
  }
}

// ---------------------------------------------------------------------------
// Finalize expert_loads + aux_loss
// ---------------------------------------------------------------------------
__global__ __launch_bounds__(64) void gate_final(const float* __restrict__ ce,
                                                 const float* __restrict__ ssum,
                                                 float* __restrict__ out) {
  const int e = threadIdx.x;
  float loads = 0.f, aux = 0.f;
#pragma unroll
  for (int b = 0; b < NB; ++b) {
    float c = ce[b * 64 + e];
    loads += c;
    aux += (c / 512.0f) * (ssum[b * 64 + e] / 4096.0f);  // (S*K/E)=512, S=4096
  }
  out[(size_t)2 * TOK * KTOP + 1 + e] = loads;
#pragma unroll
  for (int off = 32; off > 0; off >>= 1) aux += __shfl_down(aux, off);
  if (e == 0) out[(size_t)2 * TOK * KTOP] = aux * (0.1f / 4.0f);  // ALPHA/B
}

extern "C" void kernel_launch(void* const* d_in, const int* in_sizes, int n_in,
                              void* d_out, int out_size, void* d_ws, size_t ws_size,
                              hipStream_t stream) {
  const float* x = (const float*)d_in[0];
  const float* w = (const float*)d_in[1];
  float* out = (float*)d_out;

  char* wpk = (char*)d_ws;                         // 32 chunks x 24 KB = 768 KB
  float* ce = (float*)(wpk + (size_t)NC * 24576);  // [NB][NE]
  float* ssum = ce + NB * NE;                      // [NB][NE]

  hipMemsetAsync(ce, 0, 2 * NB * NE * sizeof(float), stream);
  wsplit<<<dim3(64), dim3(256), 0, stream>>>(w, wpk);
  gate_fused<<<dim3(TOK / 64), dim3(512), 0, stream>>>(x, wpk, out, ce, ssum);
  gate_final<<<dim3(1), dim3(64), 0, stream>>>(ce, ssum, out);
}